// Round 5
// baseline (1442.469 us; speedup 1.0000x reference)
//
#include <hip/hip_runtime.h>
#include <math.h>
#include <stdint.h>

#define Bb 64
#define Nn 4096
#define Uu 64
#define RL 4224                         // 64*66
#define NU (Nn*Uu)
#define MATSZ ((size_t)Nn*(size_t)RL)   // elements per feature matrix
#define EW 56                           // ELL capacity per row per half (lambda~21, +7 sigma)
#define XSTR 360                        // K-stride (bf16) in gemm LDS, pad of 352

typedef __attribute__((ext_vector_type(8))) short short8;
typedef __attribute__((ext_vector_type(4))) float f32x4;
typedef unsigned int uint;
typedef unsigned short ushort;

__device__ inline uint f2bf(float f){ uint u=__float_as_uint(f); u += 0x7fffu + ((u>>16)&1u); return u>>16; }
__device__ inline uint pack2(float a,float b){
  uint ua=__float_as_uint(a); ua+=0x7fffu+((ua>>16)&1u);
  uint ub=__float_as_uint(b); ub+=0x7fffu+((ub>>16)&1u);
  return (ua>>16)|(ub&0xffff0000u);
}
__device__ inline float blo(uint u){ return __uint_as_float(u << 16); }
__device__ inline float bhi(uint u){ return __uint_as_float(u & 0xffff0000u); }

// ---------------- split-ELL extraction: lo (cols<2048) / hi (cols>=2048, stored col-2048) ----
__global__ __launch_bounds__(256) void k_fill(const float* __restrict__ sup,
                                              uint* __restrict__ plo, uint* __restrict__ phi,
                                              int* __restrict__ rcnt2) {
  const int lane = threadIdx.x & 63;
  const int row = blockIdx.x * 4 + (threadIdx.x >> 6);
  const float* rp = sup + (size_t)row * Nn;
  const unsigned long long lt = (1ull << lane) - 1ull;
  uint* lo = plo + (size_t)row * EW;
  uint* hi = phi + (size_t)row * EW;
  int offl = 0, offh = 0;
  for (int j0 = 0; j0 < 2048; j0 += 64) {
    float v = rp[j0 + lane];
    unsigned long long m = __ballot(v != 0.0f);
    if (v != 0.0f) {
      int pos = offl + (int)__popcll(m & lt);
      if (pos < EW) lo[pos] = (f2bf(v) << 16) | (uint)(j0 + lane);
    }
    offl += (int)__popcll(m);
  }
  for (int j0 = 2048; j0 < 4096; j0 += 64) {
    float v = rp[j0 + lane];
    unsigned long long m = __ballot(v != 0.0f);
    if (v != 0.0f) {
      int pos = offh + (int)__popcll(m & lt);
      if (pos < EW) hi[pos] = (f2bf(v) << 16) | (uint)(j0 + lane - 2048);
    }
    offh += (int)__popcll(m);
  }
  if (offl > EW) offl = EW;
  if (offh > EW) offh = EW;
  const int c4l = (offl + 3) & ~3, c4h = (offh + 3) & ~3;
  if (lane < c4l - offl) lo[offl + lane] = 0u;     // zero pad: contributes nothing
  if (lane < c4h - offh) hi[offh + lane] = 0u;
  if (lane == 0) { rcnt2[row*2] = c4l; rcnt2[row*2+1] = c4h; }
}

// ---------------- x0 = [inputs | hx] bf16 in [n][b][f], vectorized ----------------
__global__ __launch_bounds__(256) void k_bx0(const float* __restrict__ inp, const float* __restrict__ hx,
                                             ushort* __restrict__ x0) {
  const int n = blockIdx.x;
  const int b = threadIdx.x >> 2, q = threadIdx.x & 3;     // 4 lanes per batch row, 16 u each
  const float* hp = hx + (size_t)b*NU + (size_t)n*Uu + q*16;
  ushort* xp = x0 + (size_t)n*RL + b*66;
  #pragma unroll
  for (int i = 0; i < 4; ++i) {
    const float4 v = *(const float4*)&hp[i*4];
    const int o = 2 + q*16 + i*4;
    *(uint*)&xp[o]     = pack2(v.x, v.y);
    *(uint*)&xp[o + 2] = pack2(v.z, v.w);
  }
  if (q == 0) {
    const float2 iv = *(const float2*)&inp[(size_t)b*(size_t)(Nn*2) + (size_t)n*2];
    *(uint*)&xp[0] = pack2(iv.x, iv.y);
  }
}

// ---------------- SpMM: y = A@x (PASS2: y = 2*A@x - xsub), two-phase 80KB slab ----------------
// Slab = 2048 source rows x 16 bf16 cols, stride 20 ushorts (80 KiB) -> 2 blocks/CU, 8 waves/SIMD.
// Phase 0: stage rows [0,2048), walk lo-ELL, write partial. Phase 1: stage [2048,4096), walk
// hi-ELL (cols pre-shifted), RMW-accumulate into y (block's y slice is L2-resident).
// Grid 528 = 66 units x 8 XCDs; unit = 66*(b&7) + b>>3 keeps neighbor slabs on one XCD L2.
template<bool PASS2>
__global__ __launch_bounds__(1024) void k_spmm(const ushort* __restrict__ xin, const ushort* __restrict__ xsub,
                                               ushort* __restrict__ yout, const int* __restrict__ rcnt2,
                                               const uint* __restrict__ plo, const uint* __restrict__ phi) {
  extern __shared__ ushort slab[];             // [2048][20], cols 0..15 used
  const int t = threadIdx.x, cg = t & 3, rs = t >> 2;   // 4 lanes per row
  const int cgo = cg * 4;                               // ushort offset of lane's 4 cols
  const int unit = 66*(blockIdx.x & 7) + (blockIdx.x >> 3);
  const int s = unit / 264, sc = unit % 264, c0 = sc * 16;
  const int rb = s * Nn;
  const ushort* xs = xin + (PASS2 ? (size_t)s*MATSZ : (size_t)0) + c0;
  ushort* yo = yout + (size_t)s*MATSZ + c0;
  #pragma unroll
  for (int ph = 0; ph < 2; ++ph) {
    if (ph) __syncthreads();                   // walkers done before restage
    for (int it = 0; it < 8; ++it) {           // stage 2048 source rows
      const int j = it*256 + rs;
      *(uint2*)&slab[j*20 + cgo] = *(const uint2*)&xs[(size_t)(ph*2048 + j)*RL + cgo];
    }
    __syncthreads();
    const uint* __restrict__ pk = ph ? phi : plo;
    for (int it = 0; it < 16; ++it) {          // walk all 4096 output rows
      const int row = it*256 + rs;
      int p = (rb + row) * EW;
      const int p1 = p + rcnt2[(rb + row)*2 + ph];
      float a0 = 0.f, a1 = 0.f, a2 = 0.f, a3 = 0.f;
      for (; p < p1; p += 4) {
        const uint4 e = *(const uint4*)&pk[p];
        const uint2 w0 = *(const uint2*)&slab[(e.x & 0xffffu)*20u + cgo];
        const uint2 w1 = *(const uint2*)&slab[(e.y & 0xffffu)*20u + cgo];
        const uint2 w2 = *(const uint2*)&slab[(e.z & 0xffffu)*20u + cgo];
        const uint2 w3 = *(const uint2*)&slab[(e.w & 0xffffu)*20u + cgo];
        const float b0 = bhi(e.x), b1 = bhi(e.y), b2 = bhi(e.z), b3 = bhi(e.w);
        a0 += b0*blo(w0.x); a1 += b0*bhi(w0.x); a2 += b0*blo(w0.y); a3 += b0*bhi(w0.y);
        a0 += b1*blo(w1.x); a1 += b1*bhi(w1.x); a2 += b1*blo(w1.y); a3 += b1*bhi(w1.y);
        a0 += b2*blo(w2.x); a1 += b2*bhi(w2.x); a2 += b2*blo(w2.y); a3 += b2*bhi(w2.y);
        a0 += b3*blo(w3.x); a1 += b3*bhi(w3.x); a2 += b3*blo(w3.y); a3 += b3*bhi(w3.y);
      }
      const size_t oo = (size_t)row*RL + cgo;
      uint2 o;
      if (ph == 0) {
        if (PASS2) { o.x = pack2(2.f*a0, 2.f*a1); o.y = pack2(2.f*a2, 2.f*a3); }
        else       { o.x = pack2(a0, a1);         o.y = pack2(a2, a3); }
      } else {
        const uint2 yv = *(const uint2*)&yo[oo];
        if (PASS2) {
          const uint2 xv = *(const uint2*)&xsub[(size_t)row*RL + c0 + cgo];
          o.x = pack2(blo(yv.x) + 2.f*a0 - blo(xv.x), bhi(yv.x) + 2.f*a1 - bhi(xv.x));
          o.y = pack2(blo(yv.y) + 2.f*a2 - blo(xv.y), bhi(yv.y) + 2.f*a3 - bhi(xv.y));
        } else {
          o.x = pack2(blo(yv.x) + a0, bhi(yv.x) + a1);
          o.y = pack2(blo(yv.y) + a2, bhi(yv.y) + a3);
        }
      }
      *(uint2*)&yo[oo] = o;
    }
  }
}

// ---------------- W pre-pack into MFMA B-fragment order (bf16) ----------------
__global__ __launch_bounds__(256) void k_wpack(const float* __restrict__ W1, const float* __restrict__ W2,
                                               ushort* __restrict__ Wp1, ushort* __restrict__ Wp2) {
  const int tid = blockIdx.x*256 + threadIdx.x;
  const int i = tid & 7, l = (tid >> 3) & 63;
  if (tid < 45056) {
    const int g = tid >> 9, tt = g / 11, kk = g % 11;
    const int r = kk*32 + (l>>4)*8 + i, c = tt*16 + (l & 15);
    Wp1[tid] = (r < 330) ? (ushort)f2bf(W1[(size_t)r*128 + c]) : (ushort)0;
  } else {
    const int t2 = tid - 45056;
    const int g = t2 >> 9, tt = g / 11, kk = g % 11;
    const int r = kk*32 + (l>>4)*8 + i, c = tt*16 + (l & 15);
    Wp2[t2] = (r < 330) ? (ushort)f2bf(W2[(size_t)r*64 + c]) : (ushort)0;
  }
}

// ---------------- gconv1 output GEMM (MFMA), fused sigmoid + r*hx + u ----------------
__global__ __launch_bounds__(256) void k_gemm1(const ushort* __restrict__ x0, const ushort* __restrict__ y1,
                                               const ushort* __restrict__ y2, const ushort* __restrict__ Wp,
                                               const float* __restrict__ bias, const float* __restrict__ hx,
                                               ushort* __restrict__ x0w, ushort* __restrict__ ubuf) {
  __shared__ ushort Xs[64*XSTR];                  // [b][k], k = f*5+m, padded to 352
  const int n = blockIdx.x, t = threadIdx.x;
  for (int q = t; q < 64*XSTR/4; q += 256) ((unsigned long long*)Xs)[q] = 0ull;
  __syncthreads();
  for (int m = 0; m < 5; ++m) {
    const ushort* mp;
    if (m == 0) mp = x0; else { mp = (m & 1) ? y1 : y2; if (m >= 3) mp += MATSZ; }
    mp += (size_t)n * RL;
    for (int q = t; q < RL; q += 256) {
      const int b = q / 66, f = q - b*66;
      Xs[b*XSTR + f*5 + m] = mp[q];
    }
  }
  __syncthreads();
  const int w = t >> 6, l = t & 63;
  const int b0 = w * 16;
  f32x4 acc[8];
  for (int i = 0; i < 8; ++i) acc[i] = (f32x4){0.f,0.f,0.f,0.f};
  const int arow = b0 + (l & 15), koff0 = (l >> 4) * 8;
  for (int kk = 0; kk < 11; ++kk) {
    const short8 af = *(const short8*)&Xs[arow*XSTR + kk*32 + koff0];
    #pragma unroll
    for (int tt = 0; tt < 8; ++tt) {
      const short8 bf = *(const short8*)&Wp[(((size_t)tt*11 + kk)*64 + l)*8];
      acc[tt] = __builtin_amdgcn_mfma_f32_16x16x32_bf16(af, bf, acc[tt], 0, 0, 0);
    }
  }
  const int rg = (l >> 4) * 4;
  #pragma unroll
  for (int tt = 0; tt < 8; ++tt) {
    const int o = tt*16 + (l & 15);
    const float bs = bias[o];
    #pragma unroll
    for (int r = 0; r < 4; ++r) {
      const int b = b0 + rg + r;
      const float v = acc[tt][r] + bs;
      const float sg = 1.0f / (1.0f + __expf(-v));
      if (o < Uu) {
        const float h = hx[(size_t)b*NU + (size_t)n*Uu + o];
        x0w[(size_t)n*RL + b*66 + 2 + o] = (ushort)f2bf(sg * h);
      } else {
        ubuf[(size_t)b*NU + (size_t)n*Uu + (o - Uu)] = (ushort)f2bf(sg);
      }
    }
  }
}

// ---------------- gconv2 output GEMM (MFMA), fused tanh + final gate ----------------
__global__ __launch_bounds__(256) void k_gemm2(const ushort* __restrict__ x0, const ushort* __restrict__ y1,
                                               const ushort* __restrict__ y2, const ushort* __restrict__ Wp,
                                               const float* __restrict__ bias, const float* __restrict__ hx,
                                               const ushort* __restrict__ ubuf, float* __restrict__ out) {
  __shared__ ushort Xs[64*XSTR];
  const int n = blockIdx.x, t = threadIdx.x;
  for (int q = t; q < 64*XSTR/4; q += 256) ((unsigned long long*)Xs)[q] = 0ull;
  __syncthreads();
  for (int m = 0; m < 5; ++m) {
    const ushort* mp;
    if (m == 0) mp = x0; else { mp = (m & 1) ? y1 : y2; if (m >= 3) mp += MATSZ; }
    mp += (size_t)n * RL;
    for (int q = t; q < RL; q += 256) {
      const int b = q / 66, f = q - b*66;
      Xs[b*XSTR + f*5 + m] = mp[q];
    }
  }
  __syncthreads();
  const int w = t >> 6, l = t & 63;
  const int b0 = w * 16;
  f32x4 acc[4];
  for (int i = 0; i < 4; ++i) acc[i] = (f32x4){0.f,0.f,0.f,0.f};
  const int arow = b0 + (l & 15), koff0 = (l >> 4) * 8;
  for (int kk = 0; kk < 11; ++kk) {
    const short8 af = *(const short8*)&Xs[arow*XSTR + kk*32 + koff0];
    #pragma unroll
    for (int tt = 0; tt < 4; ++tt) {
      const short8 bf = *(const short8*)&Wp[(((size_t)tt*11 + kk)*64 + l)*8];
      acc[tt] = __builtin_amdgcn_mfma_f32_16x16x32_bf16(af, bf, acc[tt], 0, 0, 0);
    }
  }
  const int rg = (l >> 4) * 4;
  #pragma unroll
  for (int tt = 0; tt < 4; ++tt) {
    const int o = tt*16 + (l & 15);
    const float bs = bias[o];
    #pragma unroll
    for (int r = 0; r < 4; ++r) {
      const int b = b0 + rg + r;
      const float c = tanhf(acc[tt][r] + bs);
      const size_t ix = (size_t)b*NU + (size_t)n*Uu + o;
      const float u = __uint_as_float(((uint)ubuf[ix]) << 16);
      const float h = hx[ix];
      out[ix] = u*h + (1.0f - u)*c;
    }
  }
}

extern "C" void kernel_launch(void* const* d_in, const int* in_sizes, int n_in,
                              void* d_out, int out_size, void* d_ws, size_t ws_size,
                              hipStream_t stream) {
  const float* inp = (const float*)d_in[0];
  const float* hx  = (const float*)d_in[1];
  const float* sup = (const float*)d_in[2];
  const float* ruW = (const float*)d_in[3];
  const float* ruB = (const float*)d_in[4];
  const float* gW  = (const float*)d_in[5];
  const float* gB  = (const float*)d_in[6];
  float* out = (float*)d_out;

  // workspace (bf16 intermediates): x0 | y1[2] | y2[2] | u | Wpk | split-ELL
  ushort* x0   = (ushort*)d_ws;
  ushort* y1   = x0 + MATSZ;
  ushort* y2   = y1 + 2*MATSZ;
  ushort* ubuf = y2 + 2*MATSZ;
  ushort* Wp1  = ubuf + (size_t)Bb*NU;
  ushort* Wp2  = Wp1 + 45056;
  uint* plo = (uint*)(Wp2 + 22528);           // 8192*56 uints, rows 16B-aligned (56*4=224)
  uint* phi = plo + (size_t)8192*EW;
  int* rcnt2 = (int*)(phi + (size_t)8192*EW);

  hipFuncSetAttribute(reinterpret_cast<const void*>(&k_spmm<false>),
                      hipFuncAttributeMaxDynamicSharedMemorySize, 81920);
  hipFuncSetAttribute(reinterpret_cast<const void*>(&k_spmm<true>),
                      hipFuncAttributeMaxDynamicSharedMemorySize, 81920);

  k_fill<<<2048, 256, 0, stream>>>(sup, plo, phi, rcnt2);
  k_wpack<<<264, 256, 0, stream>>>(ruW, gW, Wp1, Wp2);
  k_bx0<<<Nn, 256, 0, stream>>>(inp, hx, x0);

  // gconv1
  k_spmm<false><<<528, 1024, 81920, stream>>>(x0, nullptr, y1, rcnt2, plo, phi);
  k_spmm<true ><<<528, 1024, 81920, stream>>>(y1, x0,      y2, rcnt2, plo, phi);
  k_gemm1<<<Nn, 256, 0, stream>>>(x0, y1, y2, Wp1, ruB, hx, x0, ubuf);
  // gconv2 (x0 state slots now hold bf16(r*hx))
  k_spmm<false><<<528, 1024, 81920, stream>>>(x0, nullptr, y1, rcnt2, plo, phi);
  k_spmm<true ><<<528, 1024, 81920, stream>>>(y1, x0,      y2, rcnt2, plo, phi);
  k_gemm2<<<Nn, 256, 0, stream>>>(x0, y1, y2, Wp2, gB, hx, ubuf, out);
}

// Round 6
// 1336.778 us; speedup vs baseline: 1.0791x; 1.0791x over previous
//
#include <hip/hip_runtime.h>
#include <math.h>
#include <stdint.h>

#define Bb 64
#define Nn 4096
#define Uu 64
#define RL 4224                         // 64*66
#define NU (Nn*Uu)
#define MATSZ ((size_t)Nn*(size_t)RL)   // elements per feature matrix
#define ELLW 112                        // ELL row capacity (avg nnz ~42)
#define XSTR 360                        // K-stride (bf16) in gemm LDS, pad of 352

typedef __attribute__((ext_vector_type(8))) short short8;
typedef __attribute__((ext_vector_type(4))) float f32x4;
typedef unsigned int uint;
typedef unsigned short ushort;

__device__ inline uint f2bf(float f){ uint u=__float_as_uint(f); u += 0x7fffu + ((u>>16)&1u); return u>>16; }
__device__ inline uint pack2(float a,float b){
  uint ua=__float_as_uint(a); ua+=0x7fffu+((ua>>16)&1u);
  uint ub=__float_as_uint(b); ub+=0x7fffu+((ub>>16)&1u);
  return (ua>>16)|(ub&0xffff0000u);
}
__device__ inline float blo(uint u){ return __uint_as_float(u << 16); }
__device__ inline float bhi(uint u){ return __uint_as_float(u & 0xffff0000u); }

// ---------------- ELL extraction: one pass, no scan ----------------
// pkv[row*112 + i] = (bf16(val)<<16) | col ; rcnt[row] = count rounded up to 4 (zero-padded)
__global__ __launch_bounds__(256) void k_fill(const float* __restrict__ sup,
                                              uint* __restrict__ pkv, int* __restrict__ rcnt) {
  const int lane = threadIdx.x & 63;
  const int row = blockIdx.x * 4 + (threadIdx.x >> 6);
  const float* rp = sup + (size_t)row * Nn;
  uint* outp = pkv + (size_t)row * ELLW;
  const unsigned long long lt = (1ull << lane) - 1ull;
  int off = 0;
  for (int j0 = 0; j0 < Nn; j0 += 64) {
    float v = rp[j0 + lane];
    unsigned long long m = __ballot(v != 0.0f);
    if (v != 0.0f) {
      int pos = off + (int)__popcll(m & lt);
      if (pos < ELLW) outp[pos] = (f2bf(v) << 16) | (uint)(j0 + lane);
    }
    off += (int)__popcll(m);
  }
  if (off > ELLW) off = ELLW;
  const int c4 = (off + 3) & ~3;
  if (lane < c4 - off) outp[off + lane] = 0u;    // zero pad: contributes nothing
  if (lane == 0) rcnt[row] = c4;
}

// ---------------- nnz counting-sort permutation (per support) ----------------
// perm[s*4096 + k] = k-th row by ascending padded-count bucket. Waves then get
// 32 similar-count rows -> divergence tax ~1.33x -> ~1.05x. Order within a
// bucket is atomic-scheduling-dependent but outputs are value-deterministic
// (each row's result is independent of which wave computes it).
__global__ __launch_bounds__(1024) void k_perm(const int* __restrict__ rcnt, int* __restrict__ perm) {
  __shared__ int base[32];
  const int s = blockIdx.x, t = threadIdx.x;
  if (t < 32) base[t] = 0;
  __syncthreads();
  for (int r = t; r < 4096; r += 1024) atomicAdd(&base[rcnt[s*4096 + r] >> 2], 1);
  __syncthreads();
  if (t == 0) { int acc = 0; for (int i = 0; i < 32; ++i) { int h = base[i]; base[i] = acc; acc += h; } }
  __syncthreads();
  for (int r = t; r < 4096; r += 1024) {
    const int pos = atomicAdd(&base[rcnt[s*4096 + r] >> 2], 1);
    perm[s*4096 + pos] = r;
  }
}

// ---------------- x0 = [inputs | hx] bf16 in [n][b][f], vectorized ----------------
__global__ __launch_bounds__(256) void k_bx0(const float* __restrict__ inp, const float* __restrict__ hx,
                                             ushort* __restrict__ x0) {
  const int n = blockIdx.x;
  const int b = threadIdx.x >> 2, q = threadIdx.x & 3;
  const float* hp = hx + (size_t)b*NU + (size_t)n*Uu + q*16;
  ushort* xp = x0 + (size_t)n*RL + b*66;
  #pragma unroll
  for (int i = 0; i < 4; ++i) {
    const float4 v = *(const float4*)&hp[i*4];
    const int o = 2 + q*16 + i*4;
    *(uint*)&xp[o]     = pack2(v.x, v.y);
    *(uint*)&xp[o + 2] = pack2(v.z, v.w);
  }
  if (q == 0) {
    const float2 iv = *(const float2*)&inp[(size_t)b*(size_t)(Nn*2) + (size_t)n*2];
    *(uint*)&xp[0] = pack2(iv.x, iv.y);
  }
}

// ---------------- SpMM, 8-col slab, 2 blocks/CU ----------------
// Slab = 4096 rows x 8 bf16 cols, unpadded (64 KiB static) -> 2 blocks/CU, 8 waves/SIMD.
// Walk j is data-random -> bank slots (j%8, cg) uniform; no padding needed.
// PASS1 (y1 = A@x): stage x0 once, walk both supports. PASS2 (y2 = 2*A@y1 - x0):
// per support stage y1_s then walk. Schedule: 512 primary units (XCD-chunked) +
// 16 leftover units row-split 32-way => ~1.03 units/block, full co-residency.
#define PROC4(E)                                                                              \
  {                                                                                           \
    const uint A0 = (E.x << 4) & 0xffff0u; const uint2 w0 = *(const uint2*)(slb + A0 + cg8);  \
    const uint A1 = (E.y << 4) & 0xffff0u; const uint2 w1 = *(const uint2*)(slb + A1 + cg8);  \
    const uint A2 = (E.z << 4) & 0xffff0u; const uint2 w2 = *(const uint2*)(slb + A2 + cg8);  \
    const uint A3 = (E.w << 4) & 0xffff0u; const uint2 w3 = *(const uint2*)(slb + A3 + cg8);  \
    const float b0 = bhi(E.x), b1 = bhi(E.y), b2 = bhi(E.z), b3 = bhi(E.w);                   \
    a0 += b0*blo(w0.x); a1 += b0*bhi(w0.x); a2 += b0*blo(w0.y); a3 += b0*bhi(w0.y);           \
    a0 += b1*blo(w1.x); a1 += b1*bhi(w1.x); a2 += b1*blo(w1.y); a3 += b1*bhi(w1.y);           \
    a0 += b2*blo(w2.x); a1 += b2*bhi(w2.x); a2 += b2*blo(w2.y); a3 += b2*bhi(w2.y);           \
    a0 += b3*blo(w3.x); a1 += b3*bhi(w3.x); a2 += b3*blo(w3.y); a3 += b3*bhi(w3.y);           \
  }

template<bool PASS2>
__global__ __launch_bounds__(1024, 8) void k_spmm(const ushort* __restrict__ xin,
                                                  const ushort* __restrict__ xsub,
                                                  ushort* __restrict__ yout,
                                                  const int* __restrict__ rcnt,
                                                  const uint* __restrict__ pkv,
                                                  const int* __restrict__ perm) {
  __shared__ ushort slab[4096*8];                        // 64 KiB
  const char* slb = (const char*)slab;
  const int t = threadIdx.x, cg = t & 1, rh = t >> 1;
  const int cg8 = cg * 8;
  const int b = blockIdx.x;
  #pragma unroll 1
  for (int task = 0; task < 2; ++task) {
    int unit, r0, nr;
    if (task == 0) { unit = ((b & 7) << 6) + (b >> 3); r0 = 0; nr = 4096; }
    else           { unit = 512 + (b >> 5); r0 = (b & 31) * 128; nr = 128; }
    const int c0 = unit * 8;
    #pragma unroll 1
    for (int s = 0; s < 2; ++s) {
      if (PASS2 || s == 0) {                             // pass1 shares the x0 slab across supports
        if (task | s) __syncthreads();                   // walkers done before restage
        const ushort* src = xin + (PASS2 ? (size_t)s * MATSZ : (size_t)0) + c0;
        #pragma unroll
        for (int it = 0; it < 4; ++it) {
          const int j = it * 1024 + t;
          *(uint4*)&slab[j * 8] = *(const uint4*)&src[(size_t)j * RL];
        }
        __syncthreads();
      }
      const int sb = s << 12;
      ushort* yo = yout + (size_t)s * MATSZ + c0;
      for (int r = r0 + rh; r < r0 + nr; r += 512) {
        const int row = perm[sb + r];
        const int rb = sb + row;
        int p = rb * ELLW;
        const int pe = p + rcnt[rb];
        float a0 = 0.f, a1 = 0.f, a2 = 0.f, a3 = 0.f;
        uint4 e = *(const uint4*)&pkv[p]; p += 4;
        for (; p < pe; p += 4) {                         // prefetch next batch, then process
          const uint4 en = *(const uint4*)&pkv[p];
          PROC4(e);
          e = en;
        }
        PROC4(e);
        const size_t oo = (size_t)row * RL + cg * 4;
        uint2 o;
        if (PASS2) {
          const uint2 xv = *(const uint2*)&xsub[oo + c0];
          o.x = pack2(2.f*a0 - blo(xv.x), 2.f*a1 - bhi(xv.x));
          o.y = pack2(2.f*a2 - blo(xv.y), 2.f*a3 - bhi(xv.y));
        } else {
          o.x = pack2(a0, a1); o.y = pack2(a2, a3);
        }
        *(uint2*)&yo[oo] = o;
      }
    }
  }
}

// ---------------- W pre-pack into MFMA B-fragment order (bf16) ----------------
__global__ __launch_bounds__(256) void k_wpack(const float* __restrict__ W1, const float* __restrict__ W2,
                                               ushort* __restrict__ Wp1, ushort* __restrict__ Wp2) {
  const int tid = blockIdx.x*256 + threadIdx.x;
  const int i = tid & 7, l = (tid >> 3) & 63;
  if (tid < 45056) {
    const int g = tid >> 9, tt = g / 11, kk = g % 11;
    const int r = kk*32 + (l>>4)*8 + i, c = tt*16 + (l & 15);
    Wp1[tid] = (r < 330) ? (ushort)f2bf(W1[(size_t)r*128 + c]) : (ushort)0;
  } else {
    const int t2 = tid - 45056;
    const int g = t2 >> 9, tt = g / 11, kk = g % 11;
    const int r = kk*32 + (l>>4)*8 + i, c = tt*16 + (l & 15);
    Wp2[t2] = (r < 330) ? (ushort)f2bf(W2[(size_t)r*64 + c]) : (ushort)0;
  }
}

// ---------------- gconv1 output GEMM (MFMA), fused sigmoid + r*hx + u ----------------
__global__ __launch_bounds__(256) void k_gemm1(const ushort* __restrict__ x0, const ushort* __restrict__ y1,
                                               const ushort* __restrict__ y2, const ushort* __restrict__ Wp,
                                               const float* __restrict__ bias, const float* __restrict__ hx,
                                               ushort* __restrict__ x0w, ushort* __restrict__ ubuf) {
  __shared__ ushort Xs[64*XSTR];
  const int n = blockIdx.x, t = threadIdx.x;
  for (int q = t; q < 64*XSTR/4; q += 256) ((unsigned long long*)Xs)[q] = 0ull;
  __syncthreads();
  for (int m = 0; m < 5; ++m) {
    const ushort* mp;
    if (m == 0) mp = x0; else { mp = (m & 1) ? y1 : y2; if (m >= 3) mp += MATSZ; }
    mp += (size_t)n * RL;
    for (int q = t; q < RL; q += 256) {
      const int b = q / 66, f = q - b*66;
      Xs[b*XSTR + f*5 + m] = mp[q];
    }
  }
  __syncthreads();
  const int w = t >> 6, l = t & 63;
  const int b0 = w * 16;
  f32x4 acc[8];
  for (int i = 0; i < 8; ++i) acc[i] = (f32x4){0.f,0.f,0.f,0.f};
  const int arow = b0 + (l & 15), koff0 = (l >> 4) * 8;
  for (int kk = 0; kk < 11; ++kk) {
    const short8 af = *(const short8*)&Xs[arow*XSTR + kk*32 + koff0];
    #pragma unroll
    for (int tt = 0; tt < 8; ++tt) {
      const short8 bf = *(const short8*)&Wp[(((size_t)tt*11 + kk)*64 + l)*8];
      acc[tt] = __builtin_amdgcn_mfma_f32_16x16x32_bf16(af, bf, acc[tt], 0, 0, 0);
    }
  }
  const int rg = (l >> 4) * 4;
  #pragma unroll
  for (int tt = 0; tt < 8; ++tt) {
    const int o = tt*16 + (l & 15);
    const float bs = bias[o];
    #pragma unroll
    for (int r = 0; r < 4; ++r) {
      const int b = b0 + rg + r;
      const float v = acc[tt][r] + bs;
      const float sg = 1.0f / (1.0f + __expf(-v));
      if (o < Uu) {
        const float h = hx[(size_t)b*NU + (size_t)n*Uu + o];
        x0w[(size_t)n*RL + b*66 + 2 + o] = (ushort)f2bf(sg * h);
      } else {
        ubuf[(size_t)b*NU + (size_t)n*Uu + (o - Uu)] = (ushort)f2bf(sg);
      }
    }
  }
}

// ---------------- gconv2 output GEMM (MFMA), fused tanh + final gate ----------------
__global__ __launch_bounds__(256) void k_gemm2(const ushort* __restrict__ x0, const ushort* __restrict__ y1,
                                               const ushort* __restrict__ y2, const ushort* __restrict__ Wp,
                                               const float* __restrict__ bias, const float* __restrict__ hx,
                                               const ushort* __restrict__ ubuf, float* __restrict__ out) {
  __shared__ ushort Xs[64*XSTR];
  const int n = blockIdx.x, t = threadIdx.x;
  for (int q = t; q < 64*XSTR/4; q += 256) ((unsigned long long*)Xs)[q] = 0ull;
  __syncthreads();
  for (int m = 0; m < 5; ++m) {
    const ushort* mp;
    if (m == 0) mp = x0; else { mp = (m & 1) ? y1 : y2; if (m >= 3) mp += MATSZ; }
    mp += (size_t)n * RL;
    for (int q = t; q < RL; q += 256) {
      const int b = q / 66, f = q - b*66;
      Xs[b*XSTR + f*5 + m] = mp[q];
    }
  }
  __syncthreads();
  const int w = t >> 6, l = t & 63;
  const int b0 = w * 16;
  f32x4 acc[4];
  for (int i = 0; i < 4; ++i) acc[i] = (f32x4){0.f,0.f,0.f,0.f};
  const int arow = b0 + (l & 15), koff0 = (l >> 4) * 8;
  for (int kk = 0; kk < 11; ++kk) {
    const short8 af = *(const short8*)&Xs[arow*XSTR + kk*32 + koff0];
    #pragma unroll
    for (int tt = 0; tt < 4; ++tt) {
      const short8 bf = *(const short8*)&Wp[(((size_t)tt*11 + kk)*64 + l)*8];
      acc[tt] = __builtin_amdgcn_mfma_f32_16x16x32_bf16(af, bf, acc[tt], 0, 0, 0);
    }
  }
  const int rg = (l >> 4) * 4;
  #pragma unroll
  for (int tt = 0; tt < 4; ++tt) {
    const int o = tt*16 + (l & 15);
    const float bs = bias[o];
    #pragma unroll
    for (int r = 0; r < 4; ++r) {
      const int b = b0 + rg + r;
      const float c = tanhf(acc[tt][r] + bs);
      const size_t ix = (size_t)b*NU + (size_t)n*Uu + o;
      const float u = __uint_as_float(((uint)ubuf[ix]) << 16);
      const float h = hx[ix];
      out[ix] = u*h + (1.0f - u)*c;
    }
  }
}

extern "C" void kernel_launch(void* const* d_in, const int* in_sizes, int n_in,
                              void* d_out, int out_size, void* d_ws, size_t ws_size,
                              hipStream_t stream) {
  const float* inp = (const float*)d_in[0];
  const float* hx  = (const float*)d_in[1];
  const float* sup = (const float*)d_in[2];
  const float* ruW = (const float*)d_in[3];
  const float* ruB = (const float*)d_in[4];
  const float* gW  = (const float*)d_in[5];
  const float* gB  = (const float*)d_in[6];
  float* out = (float*)d_out;

  // workspace (bf16 intermediates, ~244 MB): x0 | y1[2] | y2[2] | u | Wpk | ELL | perm
  ushort* x0   = (ushort*)d_ws;
  ushort* y1   = x0 + MATSZ;
  ushort* y2   = y1 + 2*MATSZ;
  ushort* ubuf = y2 + 2*MATSZ;
  ushort* Wp1  = ubuf + (size_t)Bb*NU;
  ushort* Wp2  = Wp1 + 45056;
  uint* pkv  = (uint*)(Wp2 + 22528);          // 8192*112 uints, rows 16B-aligned
  int*  rcnt = (int*)(pkv + (size_t)8192*ELLW);
  int*  perm = rcnt + 8192;

  k_fill<<<2048, 256, 0, stream>>>(sup, pkv, rcnt);
  k_perm<<<2, 1024, 0, stream>>>(rcnt, perm);
  k_wpack<<<264, 256, 0, stream>>>(ruW, gW, Wp1, Wp2);
  k_bx0<<<Nn, 256, 0, stream>>>(inp, hx, x0);

  // gconv1
  k_spmm<false><<<512, 1024, 0, stream>>>(x0, x0, y1, rcnt, pkv, perm);
  k_spmm<true ><<<512, 1024, 0, stream>>>(y1, x0, y2, rcnt, pkv, perm);
  k_gemm1<<<Nn, 256, 0, stream>>>(x0, y1, y2, Wp1, ruB, hx, x0, ubuf);
  // gconv2 (x0 state slots now hold bf16(r*hx))
  k_spmm<false><<<512, 1024, 0, stream>>>(x0, x0, y1, rcnt, pkv, perm);
  k_spmm<true ><<<512, 1024, 0, stream>>>(y1, x0, y2, rcnt, pkv, perm);
  k_gemm2<<<Nn, 256, 0, stream>>>(x0, y1, y2, Wp2, gB, hx, ubuf, out);
}